// Round 4
// baseline (243.397 us; speedup 1.0000x reference)
//
#include <hip/hip_runtime.h>

// AR(24) rollout: out[b,t,d], t in [0,168), from last 24 timesteps of x[b,:,d].
//
// Graph anatomy: dur_us includes ~216 us of harness 0xAA fills (2 x 672 MiB
// at 6.5 TB/s -- the measured achievable ceiling). Kernel floor = 100.7 MB /
// 6.5 TB/s = 15.5 us; full-graph roofline ~232 us.
// R3 FAILED: 2x redundant-compute occupancy split (+12.8 us) -- chain is not
// latency-bound; compute is pure issue (~6.7 us at float2). Reverted.
// R5 (float2 NT stores): 237.7 -> 236.2; kernel ~19.8 us. Partial.
// R6 theory: at float2, per-step FMA issue (40 ns) < per-store fair-share
// HBM drain (80 ns) -> waves run ahead, block at the vmcnt-63 cap, SIMD
// idles (in-order issue, 1 wave/SIMD). float4 (4 d per thread, dwordx4 NT,
// 1024 B/wave-inst) doubles compute between stores to ~80 ns, matching the
// drain rate -> balanced stream, no long blocks, fatter 1 KiB bursts (same
// width as the 6.5 TB/s fill kernel). Per-SIMD FMA issue 13.4 us stays just
// under the 13.5 us write-drain. 64-thread blocks spread 512 waves over all
// 256 CUs. Each d keeps the exact R0 serial FMA order -> absmax 0.0.

#define BATCH 256
#define SEQ   336
#define DIMS  512
#define ORDER 24
#define TSEQ  168

typedef float f32x4 __attribute__((ext_vector_type(4)));

__global__ __launch_bounds__(64) void ar_rollout_kernel(
    const float* __restrict__ x,     // [BATCH, SEQ, DIMS]
    const float* __restrict__ W,     // [ORDER, 1]
    const float* __restrict__ bias,  // [1]
    float* __restrict__ out)         // [BATCH, TSEQ, DIMS]
{
    // One thread per (b, d-quad): d = 4*p, covers {d..d+3}.
    const int tid = blockIdx.x * blockDim.x + threadIdx.x;  // b*(DIMS/4) + p
    const int p = tid & (DIMS / 4 - 1);
    const int b = tid >> 7;          // tid / (DIMS/4)
    if (b >= BATCH) return;
    const int d = p * 4;

    // AR coefficients (wave-uniform -> scalar broadcasts) and bias.
    float wc[ORDER];
#pragma unroll
    for (int k = 0; k < ORDER; ++k) wc[k] = W[k];
    const float bb = bias[0];

    // Init window: x[b, SEQ-ORDER+k, {d..d+3}], k = 0..23 (oldest first).
    // Consecutive lanes = consecutive float4 -> each load is a coalesced
    // 1024 B/wave dwordx4 burst.
    const f32x4* xp = (const f32x4*)(x + ((size_t)b * SEQ + (SEQ - ORDER)) * DIMS + d);
    f32x4 w[ORDER];
#pragma unroll
    for (int k = 0; k < ORDER; ++k) w[k] = xp[(size_t)k * (DIMS / 4)];

    // Rollout. At step j within a group, logical window element k lives in
    // physical register w[(j+k) % ORDER]; the new value overwrites w[j].
    // Four independent serial chains (x,y,z,w components), each with the
    // exact R0 FMA order (absmax 0.0); 4-way ILP keeps FMA issue dense and
    // paces one 1 KiB NT store per ~96 FMA instructions.
    f32x4* op = (f32x4*)(out + (size_t)b * TSEQ * DIMS + d);
#pragma unroll 1
    for (int g = 0; g < TSEQ / ORDER; ++g) {
#pragma unroll
        for (int j = 0; j < ORDER; ++j) {
            float ya = bb, yb = bb, yc = bb, yd = bb;
#pragma unroll
            for (int k = 0; k < ORDER; ++k) {
                const f32x4 wk = w[(j + k) % ORDER];
                ya = fmaf(wk.x, wc[k], ya);
                yb = fmaf(wk.y, wc[k], yb);
                yc = fmaf(wk.z, wc[k], yc);
                yd = fmaf(wk.w, wc[k], yd);
            }
            f32x4 y4;
            y4.x = ya; y4.y = yb; y4.z = yc; y4.w = yd;
            w[j] = y4;
            __builtin_nontemporal_store(y4, op);  // 88 MB stream, never re-read
            op += DIMS / 4;
        }
    }
}

extern "C" void kernel_launch(void* const* d_in, const int* in_sizes, int n_in,
                              void* d_out, int out_size, void* d_ws, size_t ws_size,
                              hipStream_t stream) {
    const float* x    = (const float*)d_in[0];
    const float* W    = (const float*)d_in[1];
    const float* bias = (const float*)d_in[2];
    // d_in[3] is tar_seq_len (==168), compile-time constant here.
    float* out = (float*)d_out;

    const int threads = 64;                          // 1 wave/block
    const int blocks  = (BATCH * DIMS / 4) / threads;  // 512 blocks -> 2 waves/CU
    ar_rollout_kernel<<<blocks, threads, 0, stream>>>(x, W, bias, out);
}

// Round 5
// 237.116 us; speedup vs baseline: 1.0265x; 1.0265x over previous
//
#include <hip/hip_runtime.h>

// AR(24) rollout: out[b,t,d], t in [0,168), from last 24 timesteps of x[b,:,d].
//
// Graph anatomy: dur_us includes ~216.4 us of harness 0xAA fills (2 x 672 MiB
// at 6.5 TB/s -- the measured achievable ceiling on this chip). Kernel floor
// = 100.7 MB / 6.5 TB/s = 15.5 us; full-graph roofline ~232 us.
//
// Empirical ladder (kernel-only us): scalar 23.4 | float2 NT 19.8 | float4 NT
// 27.0 | 2x-redundant-occupancy 34 (R3, refuted). Pattern: kernel ~=
// per-wave-FMA-issue + ~13.2 us write drain, i.e. issue and drain ADD at
// <=1 wave/SIMD. float2 minimizes the sum (wave count = 2048/width is fixed
// by the serial per-(b,d) chains; time-splitting needs redundant compute,
// refuted in R3).
// R7: single A/B vs R5 -- drop the NT flag. The 6.5 TB/s fill kernel uses
// plain write-back stores; NT bypasses L2 write-combining and has no upside
// here (nothing else wants L2). Everything else identical to R5.

#define BATCH 256
#define SEQ   336
#define DIMS  512
#define ORDER 24
#define TSEQ  168

typedef float f32x2 __attribute__((ext_vector_type(2)));

__global__ __launch_bounds__(256) void ar_rollout_kernel(
    const float* __restrict__ x,     // [BATCH, SEQ, DIMS]
    const float* __restrict__ W,     // [ORDER, 1]
    const float* __restrict__ bias,  // [1]
    float* __restrict__ out)         // [BATCH, TSEQ, DIMS]
{
    // One thread per (b, d-pair): d = 2*p, covers {d, d+1}.
    const int tid = blockIdx.x * blockDim.x + threadIdx.x;  // b*(DIMS/2) + p
    const int p = tid & (DIMS / 2 - 1);
    const int b = tid >> 8;          // tid / (DIMS/2)
    if (b >= BATCH) return;
    const int d = p * 2;

    // AR coefficients (wave-uniform -> scalar broadcasts) and bias.
    float wc[ORDER];
#pragma unroll
    for (int k = 0; k < ORDER; ++k) wc[k] = W[k];
    const float bb = bias[0];

    // Init window: x[b, SEQ-ORDER+k, {d,d+1}], k = 0..23 (oldest first).
    // Consecutive lanes = consecutive float2 -> each load is a coalesced
    // 512 B/wave dwordx2 burst.
    const f32x2* xp = (const f32x2*)(x + ((size_t)b * SEQ + (SEQ - ORDER)) * DIMS + d);
    f32x2 w[ORDER];
#pragma unroll
    for (int k = 0; k < ORDER; ++k) w[k] = xp[(size_t)k * (DIMS / 2)];

    // Rollout. At step j within a group, logical window element k lives in
    // physical register w[(j+k) % ORDER]; the new value overwrites w[j].
    // Two independent serial chains (x,y components), each with the exact
    // R0 FMA order (absmax 0.0); 2-way ILP keeps FMA issue dense.
    f32x2* op = (f32x2*)(out + (size_t)b * TSEQ * DIMS + d);
#pragma unroll 1
    for (int g = 0; g < TSEQ / ORDER; ++g) {
#pragma unroll
        for (int j = 0; j < ORDER; ++j) {
            float ya = bb;
            float yb = bb;
#pragma unroll
            for (int k = 0; k < ORDER; ++k) {
                const f32x2 wk = w[(j + k) % ORDER];
                ya = fmaf(wk.x, wc[k], ya);
                yb = fmaf(wk.y, wc[k], yb);
            }
            f32x2 y2;
            y2.x = ya;
            y2.y = yb;
            w[j] = y2;
            *op = y2;                 // plain write-back store (A/B vs R5's NT)
            op += DIMS / 2;
        }
    }
}

extern "C" void kernel_launch(void* const* d_in, const int* in_sizes, int n_in,
                              void* d_out, int out_size, void* d_ws, size_t ws_size,
                              hipStream_t stream) {
    const float* x    = (const float*)d_in[0];
    const float* W    = (const float*)d_in[1];
    const float* bias = (const float*)d_in[2];
    // d_in[3] is tar_seq_len (==168), compile-time constant here.
    float* out = (float*)d_out;

    const int threads = 256;
    const int blocks  = (BATCH * DIMS / 2) / threads;  // 256 blocks, 1/CU
    ar_rollout_kernel<<<blocks, threads, 0, stream>>>(x, W, bias, out);
}